// Round 7
// baseline (274.539 us; speedup 1.0000x reference)
//
#include <hip/hip_runtime.h>
#include <hip/hip_bf16.h>
#include <cstddef>
#include <cstdint>

// Problem constants
#define B 4
#define T 2048
#define C 1024
#define NQ 8
#define D 128
#define M_ROWS (B * T)          // 8192
#define NTOT (2 * D + NQ * D)   // 1280: [k | v | q0..q7]

typedef __bf16 bf16x8 __attribute__((ext_vector_type(8)));
typedef float  f32x4  __attribute__((ext_vector_type(4)));
typedef uint32_t u32x4 __attribute__((ext_vector_type(4)));

__device__ __forceinline__ ushort f2bf(float f) {
    union { float f; uint32_t u; } v; v.f = f;
    const uint32_t r = (v.u + 0x7fffu + ((v.u >> 16) & 1u)) >> 16;
    return (ushort)r;
}

__device__ __forceinline__ uint32_t cvt_pk_bf16(float lo, float hi) {
    uint32_t r;
    asm("v_cvt_pk_bf16_f32 %0, %1, %2" : "=v"(r) : "v"(lo), "v"(hi));
    return r;
}

__device__ __forceinline__ void gld_lds16(const ushort* g, ushort* lds_uniform) {
    __builtin_amdgcn_global_load_lds(
        (const __attribute__((address_space(1))) void*)g,
        (__attribute__((address_space(3))) void*)lds_uniform, 16, 0, 0);
}

// -------------------- x f32 -> bf16 --------------------
__global__ __launch_bounds__(256) void xcvt(const float* __restrict__ x,
                                            ushort* __restrict__ xb) {
    const size_t i = ((size_t)blockIdx.x * 256 + threadIdx.x) * 8;
    const float4 a = *(const float4*)(x + i);
    const float4 b = *(const float4*)(x + i + 4);
    uint4 o;
    o.x = f2bf(a.x) | ((uint32_t)f2bf(a.y) << 16);
    o.y = f2bf(a.z) | ((uint32_t)f2bf(a.w) << 16);
    o.z = f2bf(b.x) | ((uint32_t)f2bf(b.y) << 16);
    o.w = f2bf(b.z) | ((uint32_t)f2bf(b.w) << 16);
    *(uint4*)(xb + i) = o;
}

// -------------------- weight transpose+convert: src f32 [1024][NC] -> dst bf16 [NC][1024]
__device__ __forceinline__ void wtrans_body(const float* __restrict__ src,
                                            ushort* __restrict__ dst, int NC,
                                            int bx, int by) {
    __shared__ ushort Ts[64][72];
    const int tid = threadIdx.x;
    const int k0 = by * 64, c0 = bx * 64;
    {
        const int r = tid >> 2, cq = tid & 3;
#pragma unroll
        for (int i = 0; i < 4; ++i) {
            const int cc = cq * 16 + i * 4;
            const float4 v = *(const float4*)(src + (size_t)(k0 + r) * NC + c0 + cc);
            uint2 o;
            o.x = f2bf(v.x) | ((uint32_t)f2bf(v.y) << 16);
            o.y = f2bf(v.z) | ((uint32_t)f2bf(v.w) << 16);
            *(uint2*)(&Ts[r][cc]) = o;
        }
    }
    __syncthreads();
    {
        const int n = tid >> 2, kq = tid & 3;
        ushort vv[16];
#pragma unroll
        for (int j = 0; j < 16; ++j) vv[j] = Ts[kq * 16 + j][n];
        uint4 o0, o1;
        o0.x = vv[0] | ((uint32_t)vv[1] << 16);  o0.y = vv[2] | ((uint32_t)vv[3] << 16);
        o0.z = vv[4] | ((uint32_t)vv[5] << 16);  o0.w = vv[6] | ((uint32_t)vv[7] << 16);
        o1.x = vv[8] | ((uint32_t)vv[9] << 16);  o1.y = vv[10] | ((uint32_t)vv[11] << 16);
        o1.z = vv[12] | ((uint32_t)vv[13] << 16); o1.w = vv[14] | ((uint32_t)vv[15] << 16);
        ushort* d = dst + (size_t)(c0 + n) * C + k0 + kq * 16;
        *(uint4*)d = o0;
        *(uint4*)(d + 8) = o1;
    }
}

// z: 0 -> Wk (rows 0..127), 1 -> Wv (128..255), 2..9 -> Wq[h] (256+128h..)
__global__ __launch_bounds__(256) void wtrans_qkv(const float* __restrict__ Wk,
                                                  const float* __restrict__ Wv,
                                                  const float* __restrict__ Wq,
                                                  ushort* __restrict__ WcatT) {
    const int z = blockIdx.z;
    const float* src;
    int rbase;
    if (z == 0)      { src = Wk; rbase = 0; }
    else if (z == 1) { src = Wv; rbase = D; }
    else             { src = Wq + (size_t)(z - 2) * C * D; rbase = 2 * D + (z - 2) * D; }
    wtrans_body(src, WcatT + (size_t)rbase * C, D, blockIdx.x, blockIdx.y);
}

__global__ __launch_bounds__(256) void wtrans_p(const float* __restrict__ Wp,
                                                ushort* __restrict__ WpT) {
    wtrans_body(Wp, WpT, C, blockIdx.x, blockIdx.y);
}

// -------------------- v transpose with per-32-key MFMA-fragment permutation --
// Permutation matches the swapped-QK^T S^T register layout: the S^T output
// lane (col=query, quad) holds keys {quad*4 + r + 16*sub}. PV A-fragment slot
// j at lane quad corresponds to key-position quad*8 + j; inverse (pos p ->
// key): k(p) = (p&3) | ((p>>3)&3)<<2 | ((p>>2)&1)<<4.
__global__ __launch_bounds__(256) void vtrans(const ushort* __restrict__ qkv,
                                              ushort* __restrict__ vbT) {
    __shared__ ushort Ts[64][136];
    const int tid = threadIdx.x;
    const int kb0 = blockIdx.x * 64;
    {
        const int r = tid >> 2, cq = tid & 3;
        const ushort* src = qkv + (size_t)(kb0 + r) * NTOT + D;
#pragma unroll
        for (int i = 0; i < 4; ++i) {
            const int cc = (cq * 4 + i) * 8;
            *(uint4*)(&Ts[r][cc]) = *(const uint4*)(src + cc);
        }
    }
    __syncthreads();
    {
        const int d = tid >> 1, half = tid & 1;
        ushort vv[32];
#pragma unroll
        for (int k = 0; k < 32; ++k) vv[k] = Ts[half * 32 + k][d];
        uint32_t dw[16];
#pragma unroll
        for (int i = 0; i < 16; ++i) {
            const int p0 = 2 * i, p1 = 2 * i + 1;
            const int k0 = (p0 & 3) | (((p0 >> 3) & 3) << 2) | (((p0 >> 2) & 1) << 4);
            const int k1 = (p1 & 3) | (((p1 >> 3) & 3) << 2) | (((p1 >> 2) & 1) << 4);
            dw[i] = vv[k0] | ((uint32_t)vv[k1] << 16);
        }
        uint32_t* dst = (uint32_t*)(vbT + (size_t)d * M_ROWS + kb0 + half * 32);
#pragma unroll
        for (int i = 0; i < 4; ++i)
            *(uint4*)(dst + i * 4) = *(uint4*)(&dw[i * 4]);
    }
}

// -------------------- MFMA GEMM: A bf16 [M][1024] @ Bt bf16 [N][1024]^T -----
template <bool BF16_OUT>
__global__ __launch_bounds__(256) void gemm_mfma(const ushort* __restrict__ A,
                                                 const ushort* __restrict__ Bt,
                                                 void* __restrict__ Cout,
                                                 const float* __restrict__ bias,
                                                 const int Nout) {
    __shared__ ushort As[128 * 32];
    __shared__ ushort Bs[128 * 32];
    const int tid  = threadIdx.x;
    const int lane = tid & 63;
    const int w    = tid >> 6;
    const int col  = lane & 15;
    const int quad = lane >> 4;
    const int row0 = blockIdx.y * 128;
    const int col0 = blockIdx.x * 128;
    const int wm = w & 1, wn = w >> 1;

    const int srow = lane >> 2;
    const int skk  = (lane & 3) * 8;

    f32x4 acc[4][4];
#pragma unroll
    for (int i = 0; i < 4; ++i)
#pragma unroll
        for (int j = 0; j < 4; ++j) acc[i][j] = (f32x4){0.f, 0.f, 0.f, 0.f};

    for (int k0 = 0; k0 < C; k0 += 32) {
        __syncthreads();
#pragma unroll
        for (int j = 0; j < 2; ++j) {
            const int ci = w * 2 + j;
            const int r  = ci * 16 + srow;
            gld_lds16(A  + (size_t)(row0 + r) * C + k0 + skk, &As[ci * 512]);
            gld_lds16(Bt + (size_t)(col0 + r) * C + k0 + skk, &Bs[ci * 512]);
        }
        __syncthreads();

        bf16x8 af[4], bfr[4];
#pragma unroll
        for (int i = 0; i < 4; ++i)
            af[i] = *(const bf16x8*)&As[(wm * 64 + i * 16 + col) * 32 + quad * 8];
#pragma unroll
        for (int j = 0; j < 4; ++j)
            bfr[j] = *(const bf16x8*)&Bs[(wn * 64 + j * 16 + col) * 32 + quad * 8];
#pragma unroll
        for (int i = 0; i < 4; ++i)
#pragma unroll
            for (int j = 0; j < 4; ++j)
                acc[i][j] = __builtin_amdgcn_mfma_f32_16x16x32_bf16(af[i], bfr[j], acc[i][j], 0, 0, 0);
    }

#pragma unroll
    for (int i = 0; i < 4; ++i) {
#pragma unroll
        for (int r = 0; r < 4; ++r) {
            const int grow = row0 + wm * 64 + i * 16 + quad * 4 + r;
#pragma unroll
            for (int j = 0; j < 4; ++j) {
                const int gcol = col0 + wn * 64 + j * 16 + col;
                const float v = acc[i][j][r];
                if (BF16_OUT) {
                    ((ushort*)Cout)[(size_t)grow * Nout + gcol] = f2bf(v);
                } else {
                    ((float*)Cout)[(size_t)grow * Nout + gcol] = v + bias[gcol];
                }
            }
        }
    }
}

// -------------------- MFMA flash attention: 64 q per wave (fat waves) -------
// R7 = R2's verified shell (64-key staged tiles, 2-phase dbuf, 2 blocks/CU,
// sum-34 pair swizzle) with DOUBLE the arithmetic intensity per LDS read:
// each wave owns 64 queries (4 q-subtiles), so every K/V ds_read_b128 feeds
// 4 MFMAs instead of 2 -> per-CU DS-pipe demand halves (R2 was LDS-read-bound
// at ~77% DS utilization; R6 proved 1-block/CU can't keep the pipe fed).
// Block = 2 waves = 128 q strip; grid (16,8,4) = 512 blocks = 2/CU.
// VGPR control: S/softmax/PV run in two 32-key halves (S live = 32 regs);
// halves align with vtrans's per-32-key permutation (R6-verified pack).
// Per-wave diagonal: wave w masks only tile ntiles-2+w; wave 0 skips the
// final tile (fully masked for its queries).
__global__ __launch_bounds__(128, 2) void attn_mfma(const ushort* __restrict__ qkv,
                                                    const ushort* __restrict__ vbT,
                                                    ushort* __restrict__ attb) {
    __shared__ ushort Ks[2][4][64][32];   // [buf][d-chunk][key][32 d]   2x16 KB
    __shared__ ushort Vt[2][4][128][16];  // [buf][pos-chunk][d][16 pos] 2x16 KB

    const int tid  = threadIdx.x;
    const int lane = tid & 63;
    const int w    = tid >> 6;          // 0..1
    const int col  = lane & 15;
    const int quad = lane >> 4;
    const int h    = blockIdx.y;
    const int b    = blockIdx.z;
    const int qb_i = ((b >> 1) & 1) ? (15 - (int)blockIdx.x) : (int)blockIdx.x;
    const int q0   = qb_i * 128;

    // Q fragments: 4 q-subtiles of 16 (wave covers 64 queries)
    bf16x8 qf[4][4];
#pragma unroll
    for (int qs = 0; qs < 4; ++qs) {
        const ushort* qrow = qkv + (size_t)(b * T + q0 + w * 64 + qs * 16 + col) * NTOT + 2 * D + h * D;
#pragma unroll
        for (int kb2 = 0; kb2 < 4; ++kb2)
            qf[qs][kb2] = *(const bf16x8*)(qrow + kb2 * 32 + quad * 8);
    }

    const ushort* kbase = qkv + (size_t)b * T * NTOT;   // k at col 0
    const ushort* vbase = vbT + (size_t)b * T;          // row stride M_ROWS

    f32x4 O[4][8];
#pragma unroll
    for (int qs = 0; qs < 4; ++qs)
#pragma unroll
        for (int i = 0; i < 8; ++i) O[qs][i] = (f32x4){0.f, 0.f, 0.f, 0.f};
    float l_acc[4] = {0.f, 0.f, 0.f, 0.f};

    const int ntiles  = 2 * qb_i + 2;
    const int sk_key  = lane >> 2;
    const int sk_d    = (lane & 3) * 8;
    const int sv_d    = lane >> 1;
    const int sv_half = (lane & 1) * 8;
    const int kg0     = quad >> 1;
    const int ko      = (quad & 1) * 8;
    // scale * log2(e): 1024^-0.5 * 1.4426950408889634
    const float SC = 0.045084220f;

    // each wave stages 2 d-chunks of K and 2 pos-chunks of V (16 gld_lds)
    auto stage = [&](int it, int bufi) {
        const int s0 = it * 64;
#pragma unroll
        for (int cc = 0; cc < 2; ++cc) {
            const int c = w * 2 + cc;
#pragma unroll
            for (int kg = 0; kg < 4; ++kg)
                gld_lds16(kbase + (size_t)(s0 + kg * 16 + sk_key) * NTOT + c * 32 + sk_d,
                          &Ks[bufi][c][kg * 16][0]);
#pragma unroll
            for (int i2 = 0; i2 < 4; ++i2)
                gld_lds16(vbase + (size_t)(i2 * 32 + sv_d) * M_ROWS + s0 + c * 16 + sv_half,
                          &Vt[bufi][c][i2 * 32][0]);
        }
    };

    int cur = 0;
    stage(0, 0);
    __syncthreads();

    for (int it = 0; it < ntiles; ++it) {
        if (it + 1 < ntiles) stage(it + 1, cur ^ 1);

        // wave 0's queries are fully masked in the final tile
        const bool skip = (w == 0) && (it == ntiles - 1);
        if (!skip) {
            const int s0 = it * 64;
            const bool diag = (it == ntiles - 2 + w);

            // two 32-key halves: keeps S live-range at 32 VGPRs
#pragma unroll
            for (int hf = 0; hf < 2; ++hf) {
                // S^T = K Q^T for this half: each kf read feeds 4 q-subtiles
                f32x4 S[4][2];
#pragma unroll
                for (int qs = 0; qs < 4; ++qs)
#pragma unroll
                    for (int sub = 0; sub < 2; ++sub) S[qs][sub] = (f32x4){0.f, 0.f, 0.f, 0.f};
#pragma unroll
                for (int sub = 0; sub < 2; ++sub) {
#pragma unroll
                    for (int kb2 = 0; kb2 < 4; ++kb2) {
                        bf16x8 kf = *(const bf16x8*)(&Ks[cur][kb2][hf * 32 + sub * 16 + col][quad * 8]);
                        S[0][sub] = __builtin_amdgcn_mfma_f32_16x16x32_bf16(kf, qf[0][kb2], S[0][sub], 0, 0, 0);
                        S[1][sub] = __builtin_amdgcn_mfma_f32_16x16x32_bf16(kf, qf[1][kb2], S[1][sub], 0, 0, 0);
                        S[2][sub] = __builtin_amdgcn_mfma_f32_16x16x32_bf16(kf, qf[2][kb2], S[2][sub], 0, 0, 0);
                        S[3][sub] = __builtin_amdgcn_mfma_f32_16x16x32_bf16(kf, qf[3][kb2], S[3][sub], 0, 0, 0);
                    }
                }

                // softmax + pack to PV A-fragment (one bf16x8 per qs per half)
                bf16x8 paf[4];
#pragma unroll
                for (int qs = 0; qs < 4; ++qs) {
                    float p[2][4];
                    if (diag) {
                        const int q = q0 + w * 64 + qs * 16 + col;
#pragma unroll
                        for (int sub = 0; sub < 2; ++sub)
#pragma unroll
                            for (int r = 0; r < 4; ++r) {
                                const int key = s0 + hf * 32 + sub * 16 + quad * 4 + r;
                                const float sc = (key > q) ? -1e30f : S[qs][sub][r] * SC;
                                p[sub][r] = __builtin_amdgcn_exp2f(sc);
                            }
                    } else {
#pragma unroll
                        for (int sub = 0; sub < 2; ++sub)
#pragma unroll
                            for (int r = 0; r < 4; ++r)
                                p[sub][r] = __builtin_amdgcn_exp2f(S[qs][sub][r] * SC);
                    }
                    l_acc[qs] += (p[0][0] + p[0][1]) + (p[0][2] + p[0][3])
                               + (p[1][0] + p[1][1]) + (p[1][2] + p[1][3]);
                    u32x4 wpk;
                    wpk.x = cvt_pk_bf16(p[0][0], p[0][1]);
                    wpk.y = cvt_pk_bf16(p[0][2], p[0][3]);
                    wpk.z = cvt_pk_bf16(p[1][0], p[1][1]);
                    wpk.w = cvt_pk_bf16(p[1][2], p[1][3]);
                    paf[qs] = __builtin_bit_cast(bf16x8, wpk);
                }

                // O += P V for this half: each vf read feeds 4 q-subtiles
#pragma unroll
                for (int nt = 0; nt < 8; ++nt) {
                    bf16x8 vf = *(const bf16x8*)(&Vt[cur][hf * 2 + kg0][nt * 16 + col][ko]);
                    O[0][nt] = __builtin_amdgcn_mfma_f32_16x16x32_bf16(paf[0], vf, O[0][nt], 0, 0, 0);
                    O[1][nt] = __builtin_amdgcn_mfma_f32_16x16x32_bf16(paf[1], vf, O[1][nt], 0, 0, 0);
                    O[2][nt] = __builtin_amdgcn_mfma_f32_16x16x32_bf16(paf[2], vf, O[2][nt], 0, 0, 0);
                    O[3][nt] = __builtin_amdgcn_mfma_f32_16x16x32_bf16(paf[3], vf, O[3][nt], 0, 0, 0);
                }
            }
        }

        __syncthreads();   // next buffer staged (vmcnt drained) + all reads of cur done
        cur ^= 1;
    }

    // epilogue: l lives per lane at query=col; O rows are query=quad*4+r.
#pragma unroll
    for (int qs = 0; qs < 4; ++qs) {
        float s = l_acc[qs];
        s += __shfl_xor(s, 16);
        s += __shfl_xor(s, 32);
#pragma unroll
        for (int r = 0; r < 4; ++r) {
            const float inv = 1.0f / __shfl(s, quad * 4 + r);
            const int t = q0 + w * 64 + qs * 16 + quad * 4 + r;
            ushort* orow = attb + (size_t)(b * T + t) * C + h * D;
#pragma unroll
            for (int nt = 0; nt < 8; ++nt)
                orow[nt * 16 + col] = f2bf(O[qs][nt][r] * inv);
        }
    }
}

// -------------------- Launch --------------------
extern "C" void kernel_launch(void* const* d_in, const int* in_sizes, int n_in,
                              void* d_out, int out_size, void* d_ws, size_t ws_size,
                              hipStream_t stream) {
    const float* x  = (const float*)d_in[0];
    const float* Wk = (const float*)d_in[1];
    const float* Wv = (const float*)d_in[2];
    const float* Wq = (const float*)d_in[3];
    const float* Wp = (const float*)d_in[4];
    const float* bp = (const float*)d_in[5];
    float* out = (float*)d_out;

    char* ws = (char*)d_ws;
    ushort* xb    = (ushort*)ws;                                  // 16 MB (aliased by attb later)
    ushort* attb  = xb;
    ushort* qkv   = (ushort*)(ws + (size_t)16  * 1024 * 1024);    // 20 MB
    ushort* WcatT = (ushort*)(ws + (size_t)36  * 1024 * 1024);    // 2.5 MB
    ushort* WpT   = (ushort*)(ws + (size_t)39  * 1024 * 1024);    // 2 MB
    ushort* vbT   = (ushort*)(ws + (size_t)41  * 1024 * 1024);    // 2 MB

    // 1) conversions
    xcvt<<<(size_t)M_ROWS * C / (256 * 8), 256, 0, stream>>>(x, xb);
    wtrans_qkv<<<dim3(D / 64, C / 64, 2 + NQ), 256, 0, stream>>>(Wk, Wv, Wq, WcatT);
    wtrans_p<<<dim3(C / 64, C / 64), 256, 0, stream>>>(Wp, WpT);

    // 2) fused QKV GEMM: [8192,1024] @ [1024,1280] -> qkv bf16
    gemm_mfma<true><<<dim3(NTOT / 128, M_ROWS / 128), 256, 0, stream>>>(
        xb, WcatT, qkv, nullptr, NTOT);

    // 3) v transpose (with MFMA-fragment key permutation)
    vtrans<<<M_ROWS / 64, 256, 0, stream>>>(qkv, vbT);

    // 4) flash attention (2-phase dbuf, 2 fat waves x 64q = 128q/block)
    attn_mfma<<<dim3(T / 128, NQ, B), 128, 0, stream>>>(qkv, vbT, attb);

    // 5) projection: [8192,1024] @ [1024,1024] + bp -> out f32
    gemm_mfma<false><<<dim3(C / 128, M_ROWS / 128), 256, 0, stream>>>(
        attb, WpT, out, bp, C);
}

// Round 8
// 218.534 us; speedup vs baseline: 1.2563x; 1.2563x over previous
//
#include <hip/hip_runtime.h>
#include <hip/hip_bf16.h>
#include <cstddef>
#include <cstdint>

// Problem constants
#define B 4
#define T 2048
#define C 1024
#define NQ 8
#define D 128
#define M_ROWS (B * T)          // 8192
#define NTOT (2 * D + NQ * D)   // 1280: [k | v | q0..q7]

typedef __bf16 bf16x8 __attribute__((ext_vector_type(8)));
typedef float  f32x4  __attribute__((ext_vector_type(4)));
typedef uint32_t u32x4 __attribute__((ext_vector_type(4)));

__device__ __forceinline__ ushort f2bf(float f) {
    union { float f; uint32_t u; } v; v.f = f;
    const uint32_t r = (v.u + 0x7fffu + ((v.u >> 16) & 1u)) >> 16;
    return (ushort)r;
}

__device__ __forceinline__ uint32_t cvt_pk_bf16(float lo, float hi) {
    uint32_t r;
    asm("v_cvt_pk_bf16_f32 %0, %1, %2" : "=v"(r) : "v"(lo), "v"(hi));
    return r;
}

__device__ __forceinline__ void gld_lds16(const ushort* g, ushort* lds_uniform) {
    __builtin_amdgcn_global_load_lds(
        (const __attribute__((address_space(1))) void*)g,
        (__attribute__((address_space(3))) void*)lds_uniform, 16, 0, 0);
}

// -------------------- x f32 -> bf16 --------------------
__global__ __launch_bounds__(256) void xcvt(const float* __restrict__ x,
                                            ushort* __restrict__ xb) {
    const size_t i = ((size_t)blockIdx.x * 256 + threadIdx.x) * 8;
    const float4 a = *(const float4*)(x + i);
    const float4 b = *(const float4*)(x + i + 4);
    uint4 o;
    o.x = f2bf(a.x) | ((uint32_t)f2bf(a.y) << 16);
    o.y = f2bf(a.z) | ((uint32_t)f2bf(a.w) << 16);
    o.z = f2bf(b.x) | ((uint32_t)f2bf(b.y) << 16);
    o.w = f2bf(b.z) | ((uint32_t)f2bf(b.w) << 16);
    *(uint4*)(xb + i) = o;
}

// -------------------- weight transpose+convert: src f32 [1024][NC] -> dst bf16 [NC][1024]
__device__ __forceinline__ void wtrans_body(const float* __restrict__ src,
                                            ushort* __restrict__ dst, int NC,
                                            int bx, int by) {
    __shared__ ushort Ts[64][72];
    const int tid = threadIdx.x;
    const int k0 = by * 64, c0 = bx * 64;
    {
        const int r = tid >> 2, cq = tid & 3;
#pragma unroll
        for (int i = 0; i < 4; ++i) {
            const int cc = cq * 16 + i * 4;
            const float4 v = *(const float4*)(src + (size_t)(k0 + r) * NC + c0 + cc);
            uint2 o;
            o.x = f2bf(v.x) | ((uint32_t)f2bf(v.y) << 16);
            o.y = f2bf(v.z) | ((uint32_t)f2bf(v.w) << 16);
            *(uint2*)(&Ts[r][cc]) = o;
        }
    }
    __syncthreads();
    {
        const int n = tid >> 2, kq = tid & 3;
        ushort vv[16];
#pragma unroll
        for (int j = 0; j < 16; ++j) vv[j] = Ts[kq * 16 + j][n];
        uint4 o0, o1;
        o0.x = vv[0] | ((uint32_t)vv[1] << 16);  o0.y = vv[2] | ((uint32_t)vv[3] << 16);
        o0.z = vv[4] | ((uint32_t)vv[5] << 16);  o0.w = vv[6] | ((uint32_t)vv[7] << 16);
        o1.x = vv[8] | ((uint32_t)vv[9] << 16);  o1.y = vv[10] | ((uint32_t)vv[11] << 16);
        o1.z = vv[12] | ((uint32_t)vv[13] << 16); o1.w = vv[14] | ((uint32_t)vv[15] << 16);
        ushort* d = dst + (size_t)(c0 + n) * C + k0 + kq * 16;
        *(uint4*)d = o0;
        *(uint4*)(d + 8) = o1;
    }
}

// z: 0 -> Wk (rows 0..127), 1 -> Wv (128..255), 2..9 -> Wq[h] (256+128h..)
__global__ __launch_bounds__(256) void wtrans_qkv(const float* __restrict__ Wk,
                                                  const float* __restrict__ Wv,
                                                  const float* __restrict__ Wq,
                                                  ushort* __restrict__ WcatT) {
    const int z = blockIdx.z;
    const float* src;
    int rbase;
    if (z == 0)      { src = Wk; rbase = 0; }
    else if (z == 1) { src = Wv; rbase = D; }
    else             { src = Wq + (size_t)(z - 2) * C * D; rbase = 2 * D + (z - 2) * D; }
    wtrans_body(src, WcatT + (size_t)rbase * C, D, blockIdx.x, blockIdx.y);
}

__global__ __launch_bounds__(256) void wtrans_p(const float* __restrict__ Wp,
                                                ushort* __restrict__ WpT) {
    wtrans_body(Wp, WpT, C, blockIdx.x, blockIdx.y);
}

// -------------------- v transpose with per-32-key MFMA-fragment permutation --
// Permutation matches the swapped-QK^T S^T register layout: the S^T output
// lane (col=query, quad) holds keys {quad*4 + r + 16*sub}. PV A-fragment slot
// j at lane quad corresponds to key-position quad*8 + j; inverse (pos p ->
// key): k(p) = (p&3) | ((p>>3)&3)<<2 | ((p>>2)&1)<<4.
__global__ __launch_bounds__(256) void vtrans(const ushort* __restrict__ qkv,
                                              ushort* __restrict__ vbT) {
    __shared__ ushort Ts[64][136];
    const int tid = threadIdx.x;
    const int kb0 = blockIdx.x * 64;
    {
        const int r = tid >> 2, cq = tid & 3;
        const ushort* src = qkv + (size_t)(kb0 + r) * NTOT + D;
#pragma unroll
        for (int i = 0; i < 4; ++i) {
            const int cc = (cq * 4 + i) * 8;
            *(uint4*)(&Ts[r][cc]) = *(const uint4*)(src + cc);
        }
    }
    __syncthreads();
    {
        const int d = tid >> 1, half = tid & 1;
        ushort vv[32];
#pragma unroll
        for (int k = 0; k < 32; ++k) vv[k] = Ts[half * 32 + k][d];
        uint32_t dw[16];
#pragma unroll
        for (int i = 0; i < 16; ++i) {
            const int p0 = 2 * i, p1 = 2 * i + 1;
            const int k0 = (p0 & 3) | (((p0 >> 3) & 3) << 2) | (((p0 >> 2) & 1) << 4);
            const int k1 = (p1 & 3) | (((p1 >> 3) & 3) << 2) | (((p1 >> 2) & 1) << 4);
            dw[i] = vv[k0] | ((uint32_t)vv[k1] << 16);
        }
        uint32_t* dst = (uint32_t*)(vbT + (size_t)d * M_ROWS + kb0 + half * 32);
#pragma unroll
        for (int i = 0; i < 4; ++i)
            *(uint4*)(dst + i * 4) = *(uint4*)(&dw[i * 4]);
    }
}

// -------------------- MFMA GEMM: A bf16 [M][1024] @ Bt bf16 [N][1024]^T -----
template <bool BF16_OUT>
__global__ __launch_bounds__(256) void gemm_mfma(const ushort* __restrict__ A,
                                                 const ushort* __restrict__ Bt,
                                                 void* __restrict__ Cout,
                                                 const float* __restrict__ bias,
                                                 const int Nout) {
    __shared__ ushort As[128 * 32];
    __shared__ ushort Bs[128 * 32];
    const int tid  = threadIdx.x;
    const int lane = tid & 63;
    const int w    = tid >> 6;
    const int col  = lane & 15;
    const int quad = lane >> 4;
    const int row0 = blockIdx.y * 128;
    const int col0 = blockIdx.x * 128;
    const int wm = w & 1, wn = w >> 1;

    const int srow = lane >> 2;
    const int skk  = (lane & 3) * 8;

    f32x4 acc[4][4];
#pragma unroll
    for (int i = 0; i < 4; ++i)
#pragma unroll
        for (int j = 0; j < 4; ++j) acc[i][j] = (f32x4){0.f, 0.f, 0.f, 0.f};

    for (int k0 = 0; k0 < C; k0 += 32) {
        __syncthreads();
#pragma unroll
        for (int j = 0; j < 2; ++j) {
            const int ci = w * 2 + j;
            const int r  = ci * 16 + srow;
            gld_lds16(A  + (size_t)(row0 + r) * C + k0 + skk, &As[ci * 512]);
            gld_lds16(Bt + (size_t)(col0 + r) * C + k0 + skk, &Bs[ci * 512]);
        }
        __syncthreads();

        bf16x8 af[4], bfr[4];
#pragma unroll
        for (int i = 0; i < 4; ++i)
            af[i] = *(const bf16x8*)&As[(wm * 64 + i * 16 + col) * 32 + quad * 8];
#pragma unroll
        for (int j = 0; j < 4; ++j)
            bfr[j] = *(const bf16x8*)&Bs[(wn * 64 + j * 16 + col) * 32 + quad * 8];
#pragma unroll
        for (int i = 0; i < 4; ++i)
#pragma unroll
            for (int j = 0; j < 4; ++j)
                acc[i][j] = __builtin_amdgcn_mfma_f32_16x16x32_bf16(af[i], bfr[j], acc[i][j], 0, 0, 0);
    }

#pragma unroll
    for (int i = 0; i < 4; ++i) {
#pragma unroll
        for (int r = 0; r < 4; ++r) {
            const int grow = row0 + wm * 64 + i * 16 + quad * 4 + r;
#pragma unroll
            for (int j = 0; j < 4; ++j) {
                const int gcol = col0 + wn * 64 + j * 16 + col;
                const float v = acc[i][j][r];
                if (BF16_OUT) {
                    ((ushort*)Cout)[(size_t)grow * Nout + gcol] = f2bf(v);
                } else {
                    ((float*)Cout)[(size_t)grow * Nout + gcol] = v + bias[gcol];
                }
            }
        }
    }
}

// -------------------- MFMA flash attention: 2-group key-split, 2 blocks/CU --
// R8 = R6's verified intra-block key-split rebuilt at R2's resource shape.
// Block = 4 waves = two 2-wave GROUPS; each group owns a 64-query strip with
// its own 32 KB dual-buffered 32-key K/V stream (64 KB/block -> 2 blocks/CU,
// 8 waves/CU SUSTAINED). Every group executes exactly 33 tile-iterations:
//   group B (waves 2-3): long strip 31-x, head tiles 0..32.
//   group A (waves 0-1): short strip x tiles 0..2x+1, then storeOut mid-loop
//     and assist the long strip with tail tiles 33..63-2x  (31-2x tiles).
// All blocks identical duration -> zero concurrency tail (R2's 13.3% occ
// came from short blocks dying early). Max-free softmax makes the split
// exact; partial (O,l) merge via LDS after the loop (R6-verified).
// Staging/compute/pack layouts are byte-identical to R6's passing kernel.
__global__ __launch_bounds__(256, 2) void attn_mfma(const ushort* __restrict__ qkv,
                                                    const ushort* __restrict__ vbT,
                                                    ushort* __restrict__ attb) {
    __shared__ ushort SMEM[32768];   // 64 KB; group g at g*16384: K dbuf 2x8KB, V dbuf 2x8KB

    const int tid  = threadIdx.x;
    const int lane = tid & 63;
    const int w    = tid >> 6;          // 0..3
    const int g    = w >> 1;            // 0 = short+assist group, 1 = long-head group
    const int wq   = w & 1;             // which 32q half of the group's 64q strip
    const int col  = lane & 15;
    const int quad = lane >> 4;
    const int h    = blockIdx.y;
    const int b    = blockIdx.z;
    const int x    = blockIdx.x;        // pair index 0..15
    const int sShort = x, sLong = 31 - x;
    const int own_nt = 2 * x + 2;       // short strip's 32-key tile count

    const ushort* kraw = qkv + (size_t)b * T * NTOT;   // K at col 0 of qkv rows
    const ushort* vraw = vbT + (size_t)b * T;          // row stride M_ROWS

    // ---- Q fragments (B-operand layout), 2 q-subtiles of 16 per wave ----
    bf16x8 qf[2][4];
    auto loadQ = [&](int strip) {
#pragma unroll
        for (int qs = 0; qs < 2; ++qs) {
            const ushort* qrow = qkv + (size_t)(b * T + strip * 64 + wq * 32 + qs * 16 + col) * NTOT
                                 + 2 * D + h * D;
#pragma unroll
            for (int kb2 = 0; kb2 < 4; ++kb2)
                qf[qs][kb2] = *(const bf16x8*)(qrow + kb2 * 32 + quad * 8);
        }
    };
    loadQ(g == 0 ? sShort : sLong);

    f32x4 O[2][8];
    float l_acc[2];
    auto resetAcc = [&]() {
#pragma unroll
        for (int qs = 0; qs < 2; ++qs) {
            l_acc[qs] = 0.f;
#pragma unroll
            for (int i = 0; i < 8; ++i) O[qs][i] = (f32x4){0.f, 0.f, 0.f, 0.f};
        }
    };
    resetAcc();

    const int sk_key = lane >> 2, sk_d = (lane & 3) * 8;
    const int sv_dr  = lane >> 1, sv_po = (lane & 1) * 8;
    const int kg0 = quad >> 1, ko = (quad & 1) * 8;
    // scale * log2(e): 1024^-0.5 * 1.4426950408889634
    const float SC = 0.045084220f;

    ushort* gbase = SMEM + g * 16384;

    // stage one 32-key tile (K 8KB + V 8KB) for this group into buffer bf.
    // 2 waves x 8 gld_lds; destinations wave-uniform + lane*16B (linear).
    auto stage = [&](int bf, int kt) {
        ushort* Kd = gbase + bf * 4096;
        ushort* Vd = gbase + 8192 + bf * 4096;
        // K: wave wq covers d-chunks c = wq*2 + cc
#pragma unroll
        for (int cc = 0; cc < 2; ++cc) {
            const int c = wq * 2 + cc;
#pragma unroll
            for (int half = 0; half < 2; ++half)
                gld_lds16(kraw + (size_t)(kt * 32 + half * 16 + sk_key) * NTOT + c * 32 + sk_d,
                          Kd + c * 1024 + half * 512);
        }
        // V: wave wq covers pos-chunk pc = wq (16 of the 32 permuted positions)
#pragma unroll
        for (int i2 = 0; i2 < 4; ++i2)
            gld_lds16(vraw + (size_t)(i2 * 32 + sv_dr) * M_ROWS + kt * 32 + wq * 16 + sv_po,
                      Vd + wq * 2048 + i2 * 512);
    };

    // per-wave epilogue store (used mid-loop by group 0 for its own strip)
    auto storeOut = [&](int strip) {
#pragma unroll
        for (int qs = 0; qs < 2; ++qs) {
            float s = l_acc[qs];
            s += __shfl_xor(s, 16);
            s += __shfl_xor(s, 32);
#pragma unroll
            for (int r = 0; r < 4; ++r) {
                const float inv = 1.0f / __shfl(s, quad * 4 + r);
                const int t = strip * 64 + wq * 32 + qs * 16 + quad * 4 + r;
                ushort* orow = attb + (size_t)(b * T + t) * C + h * D;
#pragma unroll
                for (int nt = 0; nt < 8; ++nt)
                    orow[nt * 16 + col] = f2bf(O[qs][nt][r] * inv);
            }
        }
    };

    // one 32-key tile: S^T = K Q^T, softmax, O += P V   (R6-verified layout)
    auto compute = [&](int bf, int kt, int qg) {
        const ushort* Kc = gbase + bf * 4096;
        const ushort* Vc = gbase + 8192 + bf * 4096;
        f32x4 S[2][2];
#pragma unroll
        for (int qs = 0; qs < 2; ++qs)
#pragma unroll
            for (int sub = 0; sub < 2; ++sub) S[qs][sub] = (f32x4){0.f, 0.f, 0.f, 0.f};
#pragma unroll
        for (int sub = 0; sub < 2; ++sub) {
#pragma unroll
            for (int kb2 = 0; kb2 < 4; ++kb2) {
                bf16x8 kf = *(const bf16x8*)(Kc + kb2 * 1024 + (sub * 16 + col) * 32 + quad * 8);
                S[0][sub] = __builtin_amdgcn_mfma_f32_16x16x32_bf16(kf, qf[0][kb2], S[0][sub], 0, 0, 0);
                S[1][sub] = __builtin_amdgcn_mfma_f32_16x16x32_bf16(kf, qf[1][kb2], S[1][sub], 0, 0, 0);
            }
        }

        const bool msk = (kt * 32 + 31 > qg);
        bf16x8 paf[2];
#pragma unroll
        for (int qs = 0; qs < 2; ++qs) {
            float pr[2][4];
            if (msk) {
                const int q = qg + wq * 32 + qs * 16 + col;
#pragma unroll
                for (int sub = 0; sub < 2; ++sub)
#pragma unroll
                    for (int r = 0; r < 4; ++r) {
                        const int key = kt * 32 + sub * 16 + quad * 4 + r;
                        const float sc = (key > q) ? -1e30f : S[qs][sub][r] * SC;
                        pr[sub][r] = __builtin_amdgcn_exp2f(sc);
                    }
            } else {
#pragma unroll
                for (int sub = 0; sub < 2; ++sub)
#pragma unroll
                    for (int r = 0; r < 4; ++r)
                        pr[sub][r] = __builtin_amdgcn_exp2f(S[qs][sub][r] * SC);
            }
            l_acc[qs] += (pr[0][0] + pr[0][1]) + (pr[0][2] + pr[0][3])
                       + (pr[1][0] + pr[1][1]) + (pr[1][2] + pr[1][3]);
            // pack: PV A-frag slot j = (sub = j>>2, r = j&3)
            u32x4 wpk;
            wpk.x = cvt_pk_bf16(pr[0][0], pr[0][1]);
            wpk.y = cvt_pk_bf16(pr[0][2], pr[0][3]);
            wpk.z = cvt_pk_bf16(pr[1][0], pr[1][1]);
            wpk.w = cvt_pk_bf16(pr[1][2], pr[1][3]);
            paf[qs] = __builtin_bit_cast(bf16x8, wpk);
        }

#pragma unroll
        for (int nt = 0; nt < 8; ++nt) {
            bf16x8 vf = *(const bf16x8*)(Vc + kg0 * 2048 + (nt * 16 + col) * 16 + ko);
            O[0][nt] = __builtin_amdgcn_mfma_f32_16x16x32_bf16(paf[0], vf, O[0][nt], 0, 0, 0);
            O[1][nt] = __builtin_amdgcn_mfma_f32_16x16x32_bf16(paf[1], vf, O[1][nt], 0, 0, 0);
        }
    };

    // key-tile schedule: group1 -> j; group0 -> own tiles then assist tiles
    auto ktOf = [&](int j) {
        return (g == 1) ? j : (j < own_nt ? j : 33 + (j - own_nt));
    };

    int qg = (g == 0 ? sShort : sLong) * 64;

    stage(0, ktOf(0));
    __syncthreads();

    int cur = 0;
    for (int j = 0; j < 33; ++j) {
        if (j + 1 < 33) stage(cur ^ 1, ktOf(j + 1));
        if (g == 0 && j == own_nt) {
            storeOut(sShort);          // own strip complete: write it out
            resetAcc();
            loadQ(sLong);
            qg = sLong * 64;
        }
        compute(cur, ktOf(j), qg);
        __syncthreads();               // next buffer staged; all reads of cur done
        cur ^= 1;
    }

    // ---- merge: group0's assist partials (O,l) -> group1, via LDS ----
    float* Lf = (float*)SMEM;          // l partials [64]
    float* Of = Lf + 64;               // O partials [64][128] (32 KB)
    float ltot[2] = {0.f, 0.f};
    if (g == 0) {
#pragma unroll
        for (int qs = 0; qs < 2; ++qs) {
            float s = l_acc[qs];
            s += __shfl_xor(s, 16);
            s += __shfl_xor(s, 32);
            if (quad == 0) Lf[wq * 32 + qs * 16 + col] = s;
        }
    }
    __syncthreads();
    if (g == 1) {
#pragma unroll
        for (int qs = 0; qs < 2; ++qs) {
            float s = l_acc[qs];
            s += __shfl_xor(s, 16);
            s += __shfl_xor(s, 32);
            ltot[qs] = s + Lf[wq * 32 + qs * 16 + col];
        }
    }
    __syncthreads();
    if (g == 0) {
#pragma unroll
        for (int qs = 0; qs < 2; ++qs)
#pragma unroll
            for (int nt = 0; nt < 8; ++nt)
#pragma unroll
                for (int r = 0; r < 4; ++r)
                    Of[(size_t)(wq * 32 + qs * 16 + quad * 4 + r) * 128 + nt * 16 + col] = O[qs][nt][r];
    }
    __syncthreads();
    if (g == 1) {
#pragma unroll
        for (int qs = 0; qs < 2; ++qs) {
#pragma unroll
            for (int r = 0; r < 4; ++r) {
                const float inv = 1.0f / __shfl(ltot[qs], quad * 4 + r);
                const int qi = wq * 32 + qs * 16 + quad * 4 + r;
                const int t = sLong * 64 + qi;
                ushort* orow = attb + (size_t)(b * T + t) * C + h * D;
#pragma unroll
                for (int nt = 0; nt < 8; ++nt)
                    orow[nt * 16 + col] =
                        f2bf((O[qs][nt][r] + Of[(size_t)qi * 128 + nt * 16 + col]) * inv);
            }
        }
    }
}

// -------------------- Launch --------------------
extern "C" void kernel_launch(void* const* d_in, const int* in_sizes, int n_in,
                              void* d_out, int out_size, void* d_ws, size_t ws_size,
                              hipStream_t stream) {
    const float* x  = (const float*)d_in[0];
    const float* Wk = (const float*)d_in[1];
    const float* Wv = (const float*)d_in[2];
    const float* Wq = (const float*)d_in[3];
    const float* Wp = (const float*)d_in[4];
    const float* bp = (const float*)d_in[5];
    float* out = (float*)d_out;

    char* ws = (char*)d_ws;
    ushort* xb    = (ushort*)ws;                                  // 16 MB (aliased by attb later)
    ushort* attb  = xb;
    ushort* qkv   = (ushort*)(ws + (size_t)16  * 1024 * 1024);    // 20 MB
    ushort* WcatT = (ushort*)(ws + (size_t)36  * 1024 * 1024);    // 2.5 MB
    ushort* WpT   = (ushort*)(ws + (size_t)39  * 1024 * 1024);    // 2 MB
    ushort* vbT   = (ushort*)(ws + (size_t)41  * 1024 * 1024);    // 2 MB

    // 1) conversions
    xcvt<<<(size_t)M_ROWS * C / (256 * 8), 256, 0, stream>>>(x, xb);
    wtrans_qkv<<<dim3(D / 64, C / 64, 2 + NQ), 256, 0, stream>>>(Wk, Wv, Wq, WcatT);
    wtrans_p<<<dim3(C / 64, C / 64), 256, 0, stream>>>(Wp, WpT);

    // 2) fused QKV GEMM: [8192,1024] @ [1024,1280] -> qkv bf16
    gemm_mfma<true><<<dim3(NTOT / 128, M_ROWS / 128), 256, 0, stream>>>(
        xb, WcatT, qkv, nullptr, NTOT);

    // 3) v transpose (with MFMA-fragment key permutation)
    vtrans<<<M_ROWS / 64, 256, 0, stream>>>(qkv, vbT);

    // 4) flash attention: 4-wave blocks, 2-group key-split, 2 blocks/CU
    attn_mfma<<<dim3(16, NQ, B), 256, 0, stream>>>(qkv, vbT, attb);

    // 5) projection: [8192,1024] @ [1024,1024] + bp -> out f32
    gemm_mfma<false><<<dim3(C / 128, M_ROWS / 128), 256, 0, stream>>>(
        attb, WpT, out, bp, C);
}

// Round 10
// 211.387 us; speedup vs baseline: 1.2988x; 1.0338x over previous
//
#include <hip/hip_runtime.h>
#include <hip/hip_bf16.h>
#include <cstddef>
#include <cstdint>

// Problem constants
#define B 4
#define T 2048
#define C 1024
#define NQ 8
#define D 128
#define M_ROWS (B * T)          // 8192
#define NTOT (2 * D + NQ * D)   // 1280: [k | v | q0..q7]

typedef __bf16 bf16x8 __attribute__((ext_vector_type(8)));
typedef float  f32x4  __attribute__((ext_vector_type(4)));
typedef uint32_t u32x4 __attribute__((ext_vector_type(4)));

__device__ __forceinline__ ushort f2bf(float f) {
    union { float f; uint32_t u; } v; v.f = f;
    const uint32_t r = (v.u + 0x7fffu + ((v.u >> 16) & 1u)) >> 16;
    return (ushort)r;
}

__device__ __forceinline__ uint32_t cvt_pk_bf16(float lo, float hi) {
    uint32_t r;
    asm("v_cvt_pk_bf16_f32 %0, %1, %2" : "=v"(r) : "v"(lo), "v"(hi));
    return r;
}

__device__ __forceinline__ void gld_lds16(const ushort* g, ushort* lds_uniform) {
    __builtin_amdgcn_global_load_lds(
        (const __attribute__((address_space(1))) void*)g,
        (__attribute__((address_space(3))) void*)lds_uniform, 16, 0, 0);
}

// -------------------- x f32 -> bf16 --------------------
__global__ __launch_bounds__(256) void xcvt(const float* __restrict__ x,
                                            ushort* __restrict__ xb) {
    const size_t i = ((size_t)blockIdx.x * 256 + threadIdx.x) * 8;
    const float4 a = *(const float4*)(x + i);
    const float4 b = *(const float4*)(x + i + 4);
    uint4 o;
    o.x = f2bf(a.x) | ((uint32_t)f2bf(a.y) << 16);
    o.y = f2bf(a.z) | ((uint32_t)f2bf(a.w) << 16);
    o.z = f2bf(b.x) | ((uint32_t)f2bf(b.y) << 16);
    o.w = f2bf(b.z) | ((uint32_t)f2bf(b.w) << 16);
    *(uint4*)(xb + i) = o;
}

// -------------------- weight transpose+convert: src f32 [1024][NC] -> dst bf16 [NC][1024]
__device__ __forceinline__ void wtrans_body(const float* __restrict__ src,
                                            ushort* __restrict__ dst, int NC,
                                            int bx, int by) {
    __shared__ ushort Ts[64][72];
    const int tid = threadIdx.x;
    const int k0 = by * 64, c0 = bx * 64;
    {
        const int r = tid >> 2, cq = tid & 3;
#pragma unroll
        for (int i = 0; i < 4; ++i) {
            const int cc = cq * 16 + i * 4;
            const float4 v = *(const float4*)(src + (size_t)(k0 + r) * NC + c0 + cc);
            uint2 o;
            o.x = f2bf(v.x) | ((uint32_t)f2bf(v.y) << 16);
            o.y = f2bf(v.z) | ((uint32_t)f2bf(v.w) << 16);
            *(uint2*)(&Ts[r][cc]) = o;
        }
    }
    __syncthreads();
    {
        const int n = tid >> 2, kq = tid & 3;
        ushort vv[16];
#pragma unroll
        for (int j = 0; j < 16; ++j) vv[j] = Ts[kq * 16 + j][n];
        uint4 o0, o1;
        o0.x = vv[0] | ((uint32_t)vv[1] << 16);  o0.y = vv[2] | ((uint32_t)vv[3] << 16);
        o0.z = vv[4] | ((uint32_t)vv[5] << 16);  o0.w = vv[6] | ((uint32_t)vv[7] << 16);
        o1.x = vv[8] | ((uint32_t)vv[9] << 16);  o1.y = vv[10] | ((uint32_t)vv[11] << 16);
        o1.z = vv[12] | ((uint32_t)vv[13] << 16); o1.w = vv[14] | ((uint32_t)vv[15] << 16);
        ushort* d = dst + (size_t)(c0 + n) * C + k0 + kq * 16;
        *(uint4*)d = o0;
        *(uint4*)(d + 8) = o1;
    }
}

// z: 0 -> Wk (rows 0..127), 1 -> Wv (128..255), 2..9 -> Wq[h] (256+128h..)
__global__ __launch_bounds__(256) void wtrans_qkv(const float* __restrict__ Wk,
                                                  const float* __restrict__ Wv,
                                                  const float* __restrict__ Wq,
                                                  ushort* __restrict__ WcatT) {
    const int z = blockIdx.z;
    const float* src;
    int rbase;
    if (z == 0)      { src = Wk; rbase = 0; }
    else if (z == 1) { src = Wv; rbase = D; }
    else             { src = Wq + (size_t)(z - 2) * C * D; rbase = 2 * D + (z - 2) * D; }
    wtrans_body(src, WcatT + (size_t)rbase * C, D, blockIdx.x, blockIdx.y);
}

__global__ __launch_bounds__(256) void wtrans_p(const float* __restrict__ Wp,
                                                ushort* __restrict__ WpT) {
    wtrans_body(Wp, WpT, C, blockIdx.x, blockIdx.y);
}

// -------------------- v transpose with per-32-key MFMA-fragment permutation --
// Permutation matches the swapped-QK^T S^T register layout: the S^T output
// lane (col=query, quad) holds keys {quad*4 + r + 16*sub}. PV A-fragment slot
// j at lane quad corresponds to key-position quad*8 + j; inverse (pos p ->
// key): k(p) = (p&3) | ((p>>3)&3)<<2 | ((p>>2)&1)<<4.
__global__ __launch_bounds__(256) void vtrans(const ushort* __restrict__ qkv,
                                              ushort* __restrict__ vbT) {
    __shared__ ushort Ts[64][136];
    const int tid = threadIdx.x;
    const int kb0 = blockIdx.x * 64;
    {
        const int r = tid >> 2, cq = tid & 3;
        const ushort* src = qkv + (size_t)(kb0 + r) * NTOT + D;
#pragma unroll
        for (int i = 0; i < 4; ++i) {
            const int cc = (cq * 4 + i) * 8;
            *(uint4*)(&Ts[r][cc]) = *(const uint4*)(src + cc);
        }
    }
    __syncthreads();
    {
        const int d = tid >> 1, half = tid & 1;
        ushort vv[32];
#pragma unroll
        for (int k = 0; k < 32; ++k) vv[k] = Ts[half * 32 + k][d];
        uint32_t dw[16];
#pragma unroll
        for (int i = 0; i < 16; ++i) {
            const int p0 = 2 * i, p1 = 2 * i + 1;
            const int k0 = (p0 & 3) | (((p0 >> 3) & 3) << 2) | (((p0 >> 2) & 1) << 4);
            const int k1 = (p1 & 3) | (((p1 >> 3) & 3) << 2) | (((p1 >> 2) & 1) << 4);
            dw[i] = vv[k0] | ((uint32_t)vv[k1] << 16);
        }
        uint32_t* dst = (uint32_t*)(vbT + (size_t)d * M_ROWS + kb0 + half * 32);
#pragma unroll
        for (int i = 0; i < 4; ++i)
            *(uint4*)(dst + i * 4) = *(uint4*)(&dw[i * 4]);
    }
}

// -------------------- MFMA GEMM: A bf16 [M][1024] @ Bt bf16 [N][1024]^T -----
// R9: BK=64 K-steps (two 32-wide sub-tiles per stage). Halves the barrier-
// pair count (32 -> 16 for K=1024) -- the vmcnt(0)+barrier drain is this
// schedule's known ~20% structural stall, and short-K shapes pay it more.
// Fragment/bank layout of each 32-wide sub-tile is byte-identical to the
// verified BK=32 form (As[kk] is the old As). LDS 32 KB -> still 4+ blocks/CU.
template <bool BF16_OUT>
__global__ __launch_bounds__(256) void gemm_mfma(const ushort* __restrict__ A,
                                                 const ushort* __restrict__ Bt,
                                                 void* __restrict__ Cout,
                                                 const float* __restrict__ bias,
                                                 const int Nout) {
    __shared__ ushort As[2][128 * 32];
    __shared__ ushort Bs[2][128 * 32];
    const int tid  = threadIdx.x;
    const int lane = tid & 63;
    const int w    = tid >> 6;
    const int col  = lane & 15;
    const int quad = lane >> 4;
    const int row0 = blockIdx.y * 128;
    const int col0 = blockIdx.x * 128;
    const int wm = w & 1, wn = w >> 1;

    const int srow = lane >> 2;
    const int skk  = (lane & 3) * 8;

    f32x4 acc[4][4];
#pragma unroll
    for (int i = 0; i < 4; ++i)
#pragma unroll
        for (int j = 0; j < 4; ++j) acc[i][j] = (f32x4){0.f, 0.f, 0.f, 0.f};

    for (int k0 = 0; k0 < C; k0 += 64) {
        __syncthreads();
#pragma unroll
        for (int kk = 0; kk < 2; ++kk) {
#pragma unroll
            for (int j = 0; j < 2; ++j) {
                const int ci = w * 2 + j;
                const int r  = ci * 16 + srow;
                gld_lds16(A  + (size_t)(row0 + r) * C + k0 + kk * 32 + skk, &As[kk][ci * 512]);
                gld_lds16(Bt + (size_t)(col0 + r) * C + k0 + kk * 32 + skk, &Bs[kk][ci * 512]);
            }
        }
        __syncthreads();

#pragma unroll
        for (int kk = 0; kk < 2; ++kk) {
            bf16x8 af[4], bfr[4];
#pragma unroll
            for (int i = 0; i < 4; ++i)
                af[i] = *(const bf16x8*)&As[kk][(wm * 64 + i * 16 + col) * 32 + quad * 8];
#pragma unroll
            for (int j = 0; j < 4; ++j)
                bfr[j] = *(const bf16x8*)&Bs[kk][(wn * 64 + j * 16 + col) * 32 + quad * 8];
#pragma unroll
            for (int i = 0; i < 4; ++i)
#pragma unroll
                for (int j = 0; j < 4; ++j)
                    acc[i][j] = __builtin_amdgcn_mfma_f32_16x16x32_bf16(af[i], bfr[j], acc[i][j], 0, 0, 0);
        }
    }

#pragma unroll
    for (int i = 0; i < 4; ++i) {
#pragma unroll
        for (int r = 0; r < 4; ++r) {
            const int grow = row0 + wm * 64 + i * 16 + quad * 4 + r;
#pragma unroll
            for (int j = 0; j < 4; ++j) {
                const int gcol = col0 + wn * 64 + j * 16 + col;
                const float v = acc[i][j][r];
                if (BF16_OUT) {
                    ((ushort*)Cout)[(size_t)grow * Nout + gcol] = f2bf(v);
                } else {
                    ((float*)Cout)[(size_t)grow * Nout + gcol] = v + bias[gcol];
                }
            }
        }
    }
}

// -------------------- MFMA flash attention, swapped-QK^T in-register P ------
// R2 (verified 53.6 us): 2-phase double-buffered K/V + 256-thread blocks
// covering 128 queries (4 waves x 32 q). Staging for tile t+1 is issued
// BEFORE computing tile t; the single barrier per tile drains vmcnt after
// ~1500 cycles of compute. 64 KB LDS -> 2 blocks/CU (8 waves/CU). Pair
// balance: co-resident blocks are (x, h, b+2); flipping qb on (b>>1)&1 makes
// each pair's tile count sum to a constant 34. Waves 0-1 skip their fully-
// masked last tile (wave-uniform branch).
__global__ __launch_bounds__(256, 2) void attn_mfma(const ushort* __restrict__ qkv,
                                                    const ushort* __restrict__ vbT,
                                                    ushort* __restrict__ attb) {
    __shared__ ushort Ks[2][4][64][32];   // [buf][d-chunk][key][32 d]   2x16 KB
    __shared__ ushort Vt[2][4][128][16];  // [buf][pos-chunk][d][16 pos] 2x16 KB

    const int tid  = threadIdx.x;
    const int lane = tid & 63;
    const int w    = tid >> 6;          // 0..3
    const int col  = lane & 15;
    const int quad = lane >> 4;
    const int h    = blockIdx.y;
    const int b    = blockIdx.z;
    const int qb_i = ((b >> 1) & 1) ? (gridDim.x - 1 - blockIdx.x) : blockIdx.x;
    const int q0   = qb_i * 128;

    // Q fragments for both q-subtiles (B-operand layout)
    bf16x8 qf[2][4];
#pragma unroll
    for (int qs = 0; qs < 2; ++qs) {
        const ushort* qrow = qkv + (size_t)(b * T + q0 + w * 32 + qs * 16 + col) * NTOT + 2 * D + h * D;
#pragma unroll
        for (int kb2 = 0; kb2 < 4; ++kb2)
            qf[qs][kb2] = *(const bf16x8*)(qrow + kb2 * 32 + quad * 8);
    }

    const ushort* kbase = qkv + (size_t)b * T * NTOT;   // k at col 0
    const ushort* vbase = vbT + (size_t)b * T;          // row stride M_ROWS

    f32x4 O[2][8];
#pragma unroll
    for (int qs = 0; qs < 2; ++qs)
#pragma unroll
        for (int i = 0; i < 8; ++i) O[qs][i] = (f32x4){0.f, 0.f, 0.f, 0.f};
    float l_acc[2] = {0.f, 0.f};

    const int ntiles  = 2 * qb_i + 2;
    const int sk_key  = lane >> 2;
    const int sk_d    = (lane & 3) * 8;
    const int sv_d    = lane >> 1;
    const int sv_half = (lane & 1) * 8;
    const int kg0     = quad >> 1;
    const int ko      = (quad & 1) * 8;
    // scale * log2(e): 1024^-0.5 * 1.4426950408889634
    const float SC = 0.045084220f;

    // each wave stages its own d-chunk of K and pos-chunk of V (8 gld_lds)
    auto stage = [&](int it, int bufi) {
        const int s0 = it * 64;
#pragma unroll
        for (int kg = 0; kg < 4; ++kg)
            gld_lds16(kbase + (size_t)(s0 + kg * 16 + sk_key) * NTOT + w * 32 + sk_d,
                      &Ks[bufi][w][kg * 16][0]);
#pragma unroll
        for (int i2 = 0; i2 < 4; ++i2)
            gld_lds16(vbase + (size_t)(i2 * 32 + sv_d) * M_ROWS + s0 + w * 16 + sv_half,
                      &Vt[bufi][w][i2 * 32][0]);
    };

    int cur = 0;
    stage(0, 0);
    __syncthreads();

    for (int it = 0; it < ntiles; ++it) {
        if (it + 1 < ntiles) stage(it + 1, cur ^ 1);

        // waves 0-1 (queries q0..q0+63) have nothing unmasked in the final tile
        const bool active = (w >= 2) || (it < ntiles - 1);
        if (active) {
            const int s0 = it * 64;

            // S^T = K Q^T: each kf fragment feeds both q-subtiles
            f32x4 S[2][4];
#pragma unroll
            for (int qs = 0; qs < 2; ++qs)
#pragma unroll
                for (int sub = 0; sub < 4; ++sub) S[qs][sub] = (f32x4){0.f, 0.f, 0.f, 0.f};
#pragma unroll
            for (int sub = 0; sub < 4; ++sub) {
#pragma unroll
                for (int kb2 = 0; kb2 < 4; ++kb2) {
                    bf16x8 kf = *(const bf16x8*)(&Ks[cur][kb2][sub * 16 + col][quad * 8]);
                    S[0][sub] = __builtin_amdgcn_mfma_f32_16x16x32_bf16(kf, qf[0][kb2], S[0][sub], 0, 0, 0);
                    S[1][sub] = __builtin_amdgcn_mfma_f32_16x16x32_bf16(kf, qf[1][kb2], S[1][sub], 0, 0, 0);
                }
            }

            // mask needed on the last two tiles (diagonal spans 128 queries)
            const bool diag = (it >= ntiles - 2);
            bf16x8 paf[2][2];
#pragma unroll
            for (int qs = 0; qs < 2; ++qs) {
                float p[4][4];
                if (diag) {
                    const int q = q0 + w * 32 + qs * 16 + col;
#pragma unroll
                    for (int sub = 0; sub < 4; ++sub)
#pragma unroll
                        for (int r = 0; r < 4; ++r) {
                            const int key = s0 + sub * 16 + quad * 4 + r;
                            const float sc = (key > q) ? -1e30f : S[qs][sub][r] * SC;
                            p[sub][r] = __builtin_amdgcn_exp2f(sc);
                        }
                } else {
#pragma unroll
                    for (int sub = 0; sub < 4; ++sub)
#pragma unroll
                        for (int r = 0; r < 4; ++r)
                            p[sub][r] = __builtin_amdgcn_exp2f(S[qs][sub][r] * SC);
                }
                float ls = 0.f;
#pragma unroll
                for (int sub = 0; sub < 4; ++sub)
                    ls += (p[sub][0] + p[sub][1]) + (p[sub][2] + p[sub][3]);
                l_acc[qs] += ls;

                // pack P -> A-fragments: slot j of kg = (sub = kg*2 + (j>>2), r = j&3)
                u32x4 w0, w1;
                w0.x = cvt_pk_bf16(p[0][0], p[0][1]);
                w0.y = cvt_pk_bf16(p[0][2], p[0][3]);
                w0.z = cvt_pk_bf16(p[1][0], p[1][1]);
                w0.w = cvt_pk_bf16(p[1][2], p[1][3]);
                w1.x = cvt_pk_bf16(p[2][0], p[2][1]);
                w1.y = cvt_pk_bf16(p[2][2], p[2][3]);
                w1.z = cvt_pk_bf16(p[3][0], p[3][1]);
                w1.w = cvt_pk_bf16(p[3][2], p[3][3]);
                paf[qs][0] = __builtin_bit_cast(bf16x8, w0);
                paf[qs][1] = __builtin_bit_cast(bf16x8, w1);
            }

            // O += P V: V fragments shared across the 2 q-subtiles
#pragma unroll
            for (int nt = 0; nt < 8; ++nt) {
                bf16x8 vf0 = *(const bf16x8*)(&Vt[cur][kg0][nt * 16 + col][ko]);
                bf16x8 vf1 = *(const bf16x8*)(&Vt[cur][2 + kg0][nt * 16 + col][ko]);
#pragma unroll
                for (int qs = 0; qs < 2; ++qs) {
                    O[qs][nt] = __builtin_amdgcn_mfma_f32_16x16x32_bf16(paf[qs][0], vf0, O[qs][nt], 0, 0, 0);
                    O[qs][nt] = __builtin_amdgcn_mfma_f32_16x16x32_bf16(paf[qs][1], vf1, O[qs][nt], 0, 0, 0);
                }
            }
        }

        __syncthreads();   // next buffer staged (vmcnt drained) + all reads of cur done
        cur ^= 1;
    }

    // epilogue: l lives per lane at query=col; O rows are query=quad*4+r.
#pragma unroll
    for (int qs = 0; qs < 2; ++qs) {
        float s = l_acc[qs];
        s += __shfl_xor(s, 16);
        s += __shfl_xor(s, 32);
#pragma unroll
        for (int r = 0; r < 4; ++r) {
            const float inv = 1.0f / __shfl(s, quad * 4 + r);
            const int t = q0 + w * 32 + qs * 16 + quad * 4 + r;
            ushort* orow = attb + (size_t)(b * T + t) * C + h * D;
#pragma unroll
            for (int nt = 0; nt < 8; ++nt)
                orow[nt * 16 + col] = f2bf(O[qs][nt][r] * inv);
        }
    }
}

// -------------------- Launch --------------------
extern "C" void kernel_launch(void* const* d_in, const int* in_sizes, int n_in,
                              void* d_out, int out_size, void* d_ws, size_t ws_size,
                              hipStream_t stream) {
    const float* x  = (const float*)d_in[0];
    const float* Wk = (const float*)d_in[1];
    const float* Wv = (const float*)d_in[2];
    const float* Wq = (const float*)d_in[3];
    const float* Wp = (const float*)d_in[4];
    const float* bp = (const float*)d_in[5];
    float* out = (float*)d_out;

    char* ws = (char*)d_ws;
    ushort* xb    = (ushort*)ws;                                  // 16 MB (aliased by attb later)
    ushort* attb  = xb;
    ushort* qkv   = (ushort*)(ws + (size_t)16  * 1024 * 1024);    // 20 MB
    ushort* WcatT = (ushort*)(ws + (size_t)36  * 1024 * 1024);    // 2.5 MB
    ushort* WpT   = (ushort*)(ws + (size_t)39  * 1024 * 1024);    // 2 MB
    ushort* vbT   = (ushort*)(ws + (size_t)41  * 1024 * 1024);    // 2 MB

    // 1) conversions
    xcvt<<<(size_t)M_ROWS * C / (256 * 8), 256, 0, stream>>>(x, xb);
    wtrans_qkv<<<dim3(D / 64, C / 64, 2 + NQ), 256, 0, stream>>>(Wk, Wv, Wq, WcatT);
    wtrans_p<<<dim3(C / 64, C / 64), 256, 0, stream>>>(Wp, WpT);

    // 2) fused QKV GEMM: [8192,1024] @ [1024,1280] -> qkv bf16
    gemm_mfma<true><<<dim3(NTOT / 128, M_ROWS / 128), 256, 0, stream>>>(
        xb, WcatT, qkv, nullptr, NTOT);

    // 3) v transpose (with MFMA-fragment key permutation)
    vtrans<<<M_ROWS / 64, 256, 0, stream>>>(qkv, vbT);

    // 4) flash attention (R2 verified: 2-phase dbuf, 4 waves x 32q)
    attn_mfma<<<dim3(T / 128, NQ, B), 256, 0, stream>>>(qkv, vbT, attb);

    // 5) projection: [8192,1024] @ [1024,1024] + bp -> out f32
    gemm_mfma<false><<<dim3(C / 128, M_ROWS / 128), 256, 0, stream>>>(
        attb, WpT, out, bp, C);
}

// Round 12
// 203.346 us; speedup vs baseline: 1.3501x; 1.0395x over previous
//
#include <hip/hip_runtime.h>
#include <hip/hip_bf16.h>
#include <cstddef>
#include <cstdint>

// Problem constants
#define B 4
#define T 2048
#define C 1024
#define NQ 8
#define D 128
#define M_ROWS (B * T)          // 8192
#define NTOT (2 * D + NQ * D)   // 1280: [k | v | q0..q7]

typedef __bf16 bf16x8 __attribute__((ext_vector_type(8)));
typedef float  f32x4  __attribute__((ext_vector_type(4)));
typedef uint32_t u32x4 __attribute__((ext_vector_type(4)));

__device__ __forceinline__ ushort f2bf(float f) {
    union { float f; uint32_t u; } v; v.f = f;
    const uint32_t r = (v.u + 0x7fffu + ((v.u >> 16) & 1u)) >> 16;
    return (ushort)r;
}

__device__ __forceinline__ uint32_t cvt_pk_bf16(float lo, float hi) {
    uint32_t r;
    asm("v_cvt_pk_bf16_f32 %0, %1, %2" : "=v"(r) : "v"(lo), "v"(hi));
    return r;
}

__device__ __forceinline__ void gld_lds16(const ushort* g, ushort* lds_uniform) {
    __builtin_amdgcn_global_load_lds(
        (const __attribute__((address_space(1))) void*)g,
        (__attribute__((address_space(3))) void*)lds_uniform, 16, 0, 0);
}

// -------------------- x f32 -> bf16 --------------------
__global__ __launch_bounds__(256) void xcvt(const float* __restrict__ x,
                                            ushort* __restrict__ xb) {
    const size_t i = ((size_t)blockIdx.x * 256 + threadIdx.x) * 8;
    const float4 a = *(const float4*)(x + i);
    const float4 b = *(const float4*)(x + i + 4);
    uint4 o;
    o.x = f2bf(a.x) | ((uint32_t)f2bf(a.y) << 16);
    o.y = f2bf(a.z) | ((uint32_t)f2bf(a.w) << 16);
    o.z = f2bf(b.x) | ((uint32_t)f2bf(b.y) << 16);
    o.w = f2bf(b.z) | ((uint32_t)f2bf(b.w) << 16);
    *(uint4*)(xb + i) = o;
}

// -------------------- weight transpose+convert: src f32 [1024][NC] -> dst bf16 [NC][1024]
__device__ __forceinline__ void wtrans_body(const float* __restrict__ src,
                                            ushort* __restrict__ dst, int NC,
                                            int bx, int by) {
    __shared__ ushort Ts[64][72];
    const int tid = threadIdx.x;
    const int k0 = by * 64, c0 = bx * 64;
    {
        const int r = tid >> 2, cq = tid & 3;
#pragma unroll
        for (int i = 0; i < 4; ++i) {
            const int cc = cq * 16 + i * 4;
            const float4 v = *(const float4*)(src + (size_t)(k0 + r) * NC + c0 + cc);
            uint2 o;
            o.x = f2bf(v.x) | ((uint32_t)f2bf(v.y) << 16);
            o.y = f2bf(v.z) | ((uint32_t)f2bf(v.w) << 16);
            *(uint2*)(&Ts[r][cc]) = o;
        }
    }
    __syncthreads();
    {
        const int n = tid >> 2, kq = tid & 3;
        ushort vv[16];
#pragma unroll
        for (int j = 0; j < 16; ++j) vv[j] = Ts[kq * 16 + j][n];
        uint4 o0, o1;
        o0.x = vv[0] | ((uint32_t)vv[1] << 16);  o0.y = vv[2] | ((uint32_t)vv[3] << 16);
        o0.z = vv[4] | ((uint32_t)vv[5] << 16);  o0.w = vv[6] | ((uint32_t)vv[7] << 16);
        o1.x = vv[8] | ((uint32_t)vv[9] << 16);  o1.y = vv[10] | ((uint32_t)vv[11] << 16);
        o1.z = vv[12] | ((uint32_t)vv[13] << 16); o1.w = vv[14] | ((uint32_t)vv[15] << 16);
        ushort* d = dst + (size_t)(c0 + n) * C + k0 + kq * 16;
        *(uint4*)d = o0;
        *(uint4*)(d + 8) = o1;
    }
}

// z: 0 -> Wk (rows 0..127), 1 -> Wv (128..255), 2..9 -> Wq[h] (256+128h..)
__global__ __launch_bounds__(256) void wtrans_qkv(const float* __restrict__ Wk,
                                                  const float* __restrict__ Wv,
                                                  const float* __restrict__ Wq,
                                                  ushort* __restrict__ WcatT) {
    const int z = blockIdx.z;
    const float* src;
    int rbase;
    if (z == 0)      { src = Wk; rbase = 0; }
    else if (z == 1) { src = Wv; rbase = D; }
    else             { src = Wq + (size_t)(z - 2) * C * D; rbase = 2 * D + (z - 2) * D; }
    wtrans_body(src, WcatT + (size_t)rbase * C, D, blockIdx.x, blockIdx.y);
}

__global__ __launch_bounds__(256) void wtrans_p(const float* __restrict__ Wp,
                                                ushort* __restrict__ WpT) {
    wtrans_body(Wp, WpT, C, blockIdx.x, blockIdx.y);
}

// -------------------- v transpose with per-32-key MFMA-fragment permutation --
// Permutation matches the swapped-QK^T S^T register layout: the S^T output
// lane (col=query, quad) holds keys {quad*4 + r + 16*sub}. PV A-fragment slot
// j at lane quad corresponds to key-position quad*8 + j; inverse (pos p ->
// key): k(p) = (p&3) | ((p>>3)&3)<<2 | ((p>>2)&1)<<4.
__global__ __launch_bounds__(256) void vtrans(const ushort* __restrict__ qkv,
                                              ushort* __restrict__ vbT) {
    __shared__ ushort Ts[64][136];
    const int tid = threadIdx.x;
    const int kb0 = blockIdx.x * 64;
    {
        const int r = tid >> 2, cq = tid & 3;
        const ushort* src = qkv + (size_t)(kb0 + r) * NTOT + D;
#pragma unroll
        for (int i = 0; i < 4; ++i) {
            const int cc = (cq * 4 + i) * 8;
            *(uint4*)(&Ts[r][cc]) = *(const uint4*)(src + cc);
        }
    }
    __syncthreads();
    {
        const int d = tid >> 1, half = tid & 1;
        ushort vv[32];
#pragma unroll
        for (int k = 0; k < 32; ++k) vv[k] = Ts[half * 32 + k][d];
        uint32_t dw[16];
#pragma unroll
        for (int i = 0; i < 16; ++i) {
            const int p0 = 2 * i, p1 = 2 * i + 1;
            const int k0 = (p0 & 3) | (((p0 >> 3) & 3) << 2) | (((p0 >> 2) & 1) << 4);
            const int k1 = (p1 & 3) | (((p1 >> 3) & 3) << 2) | (((p1 >> 2) & 1) << 4);
            dw[i] = vv[k0] | ((uint32_t)vv[k1] << 16);
        }
        uint32_t* dst = (uint32_t*)(vbT + (size_t)d * M_ROWS + kb0 + half * 32);
#pragma unroll
        for (int i = 0; i < 4; ++i)
            *(uint4*)(dst + i * 4) = *(uint4*)(&dw[i * 4]);
    }
}

// -------------------- MFMA GEMM: A bf16 [M][1024] @ Bt bf16 [N][1024]^T -----
// R11: bijective XCD-chunk swizzle (m204 form). Dispatch slot s runs on XCD
// s%8; remapping tile = (s&7)*(nwg/8) + (s>>3) gives each XCD a CONTIGUOUS
// row-major band of tiles (8 row-panels x all cols for nwg=640/512), so the
// A row-panels shared by 10 (QKV) / 8 (proj) column-tiles stay in ONE XCD's
// L2 instead of being refetched by all 8. nwg%8==0 for both GEMMs.
// BK=64 K-steps retained from R9 (neutral, keeps 16 barrier-pairs).
template <bool BF16_OUT>
__global__ __launch_bounds__(256) void gemm_mfma(const ushort* __restrict__ A,
                                                 const ushort* __restrict__ Bt,
                                                 void* __restrict__ Cout,
                                                 const float* __restrict__ bias,
                                                 const int Nout) {
    __shared__ ushort As[2][128 * 32];
    __shared__ ushort Bs[2][128 * 32];
    const int tid  = threadIdx.x;
    const int lane = tid & 63;
    const int w    = tid >> 6;
    const int col  = lane & 15;
    const int quad = lane >> 4;

    // XCD-chunk swizzle: slot -> logical tile (row-major decode)
    const int nwg  = gridDim.x * gridDim.y;
    const int slot = blockIdx.y * gridDim.x + blockIdx.x;
    const int lid  = (slot & 7) * (nwg >> 3) + (slot >> 3);
    const int bx   = lid % gridDim.x;
    const int by   = lid / gridDim.x;
    const int row0 = by * 128;
    const int col0 = bx * 128;
    const int wm = w & 1, wn = w >> 1;

    const int srow = lane >> 2;
    const int skk  = (lane & 3) * 8;

    f32x4 acc[4][4];
#pragma unroll
    for (int i = 0; i < 4; ++i)
#pragma unroll
        for (int j = 0; j < 4; ++j) acc[i][j] = (f32x4){0.f, 0.f, 0.f, 0.f};

    for (int k0 = 0; k0 < C; k0 += 64) {
        __syncthreads();
#pragma unroll
        for (int kk = 0; kk < 2; ++kk) {
#pragma unroll
            for (int j = 0; j < 2; ++j) {
                const int ci = w * 2 + j;
                const int r  = ci * 16 + srow;
                gld_lds16(A  + (size_t)(row0 + r) * C + k0 + kk * 32 + skk, &As[kk][ci * 512]);
                gld_lds16(Bt + (size_t)(col0 + r) * C + k0 + kk * 32 + skk, &Bs[kk][ci * 512]);
            }
        }
        __syncthreads();

#pragma unroll
        for (int kk = 0; kk < 2; ++kk) {
            bf16x8 af[4], bfr[4];
#pragma unroll
            for (int i = 0; i < 4; ++i)
                af[i] = *(const bf16x8*)&As[kk][(wm * 64 + i * 16 + col) * 32 + quad * 8];
#pragma unroll
            for (int j = 0; j < 4; ++j)
                bfr[j] = *(const bf16x8*)&Bs[kk][(wn * 64 + j * 16 + col) * 32 + quad * 8];
#pragma unroll
            for (int i = 0; i < 4; ++i)
#pragma unroll
                for (int j = 0; j < 4; ++j)
                    acc[i][j] = __builtin_amdgcn_mfma_f32_16x16x32_bf16(af[i], bfr[j], acc[i][j], 0, 0, 0);
        }
    }

#pragma unroll
    for (int i = 0; i < 4; ++i) {
#pragma unroll
        for (int r = 0; r < 4; ++r) {
            const int grow = row0 + wm * 64 + i * 16 + quad * 4 + r;
#pragma unroll
            for (int j = 0; j < 4; ++j) {
                const int gcol = col0 + wn * 64 + j * 16 + col;
                const float v = acc[i][j][r];
                if (BF16_OUT) {
                    ((ushort*)Cout)[(size_t)grow * Nout + gcol] = f2bf(v);
                } else {
                    ((float*)Cout)[(size_t)grow * Nout + gcol] = v + bias[gcol];
                }
            }
        }
    }
}

// -------------------- MFMA flash attention, swapped-QK^T in-register P ------
// R2 (verified 53.6 us): 2-phase double-buffered K/V + 256-thread blocks
// covering 128 queries (4 waves x 32 q). Staging for tile t+1 is issued
// BEFORE computing tile t; the single barrier per tile drains vmcnt after
// ~1500 cycles of compute. 64 KB LDS -> 2 blocks/CU (8 waves/CU). Pair
// balance: co-resident blocks are (x, h, b+2); flipping qb on (b>>1)&1 makes
// each pair's tile count sum to a constant 34. Waves 0-1 skip their fully-
// masked last tile (wave-uniform branch).
__global__ __launch_bounds__(256, 2) void attn_mfma(const ushort* __restrict__ qkv,
                                                    const ushort* __restrict__ vbT,
                                                    ushort* __restrict__ attb) {
    __shared__ ushort Ks[2][4][64][32];   // [buf][d-chunk][key][32 d]   2x16 KB
    __shared__ ushort Vt[2][4][128][16];  // [buf][pos-chunk][d][16 pos] 2x16 KB

    const int tid  = threadIdx.x;
    const int lane = tid & 63;
    const int w    = tid >> 6;          // 0..3
    const int col  = lane & 15;
    const int quad = lane >> 4;
    const int h    = blockIdx.y;
    const int b    = blockIdx.z;
    const int qb_i = ((b >> 1) & 1) ? (gridDim.x - 1 - blockIdx.x) : blockIdx.x;
    const int q0   = qb_i * 128;

    // Q fragments for both q-subtiles (B-operand layout)
    bf16x8 qf[2][4];
#pragma unroll
    for (int qs = 0; qs < 2; ++qs) {
        const ushort* qrow = qkv + (size_t)(b * T + q0 + w * 32 + qs * 16 + col) * NTOT + 2 * D + h * D;
#pragma unroll
        for (int kb2 = 0; kb2 < 4; ++kb2)
            qf[qs][kb2] = *(const bf16x8*)(qrow + kb2 * 32 + quad * 8);
    }

    const ushort* kbase = qkv + (size_t)b * T * NTOT;   // k at col 0
    const ushort* vbase = vbT + (size_t)b * T;          // row stride M_ROWS

    f32x4 O[2][8];
#pragma unroll
    for (int qs = 0; qs < 2; ++qs)
#pragma unroll
        for (int i = 0; i < 8; ++i) O[qs][i] = (f32x4){0.f, 0.f, 0.f, 0.f};
    float l_acc[2] = {0.f, 0.f};

    const int ntiles  = 2 * qb_i + 2;
    const int sk_key  = lane >> 2;
    const int sk_d    = (lane & 3) * 8;
    const int sv_d    = lane >> 1;
    const int sv_half = (lane & 1) * 8;
    const int kg0     = quad >> 1;
    const int ko      = (quad & 1) * 8;
    // scale * log2(e): 1024^-0.5 * 1.4426950408889634
    const float SC = 0.045084220f;

    // each wave stages its own d-chunk of K and pos-chunk of V (8 gld_lds)
    auto stage = [&](int it, int bufi) {
        const int s0 = it * 64;
#pragma unroll
        for (int kg = 0; kg < 4; ++kg)
            gld_lds16(kbase + (size_t)(s0 + kg * 16 + sk_key) * NTOT + w * 32 + sk_d,
                      &Ks[bufi][w][kg * 16][0]);
#pragma unroll
        for (int i2 = 0; i2 < 4; ++i2)
            gld_lds16(vbase + (size_t)(i2 * 32 + sv_d) * M_ROWS + s0 + w * 16 + sv_half,
                      &Vt[bufi][w][i2 * 32][0]);
    };

    int cur = 0;
    stage(0, 0);
    __syncthreads();

    for (int it = 0; it < ntiles; ++it) {
        if (it + 1 < ntiles) stage(it + 1, cur ^ 1);

        // waves 0-1 (queries q0..q0+63) have nothing unmasked in the final tile
        const bool active = (w >= 2) || (it < ntiles - 1);
        if (active) {
            const int s0 = it * 64;

            // S^T = K Q^T: each kf fragment feeds both q-subtiles
            f32x4 S[2][4];
#pragma unroll
            for (int qs = 0; qs < 2; ++qs)
#pragma unroll
                for (int sub = 0; sub < 4; ++sub) S[qs][sub] = (f32x4){0.f, 0.f, 0.f, 0.f};
#pragma unroll
            for (int sub = 0; sub < 4; ++sub) {
#pragma unroll
                for (int kb2 = 0; kb2 < 4; ++kb2) {
                    bf16x8 kf = *(const bf16x8*)(&Ks[cur][kb2][sub * 16 + col][quad * 8]);
                    S[0][sub] = __builtin_amdgcn_mfma_f32_16x16x32_bf16(kf, qf[0][kb2], S[0][sub], 0, 0, 0);
                    S[1][sub] = __builtin_amdgcn_mfma_f32_16x16x32_bf16(kf, qf[1][kb2], S[1][sub], 0, 0, 0);
                }
            }

            // mask needed on the last two tiles (diagonal spans 128 queries)
            const bool diag = (it >= ntiles - 2);
            bf16x8 paf[2][2];
#pragma unroll
            for (int qs = 0; qs < 2; ++qs) {
                float p[4][4];
                if (diag) {
                    const int q = q0 + w * 32 + qs * 16 + col;
#pragma unroll
                    for (int sub = 0; sub < 4; ++sub)
#pragma unroll
                        for (int r = 0; r < 4; ++r) {
                            const int key = s0 + sub * 16 + quad * 4 + r;
                            const float sc = (key > q) ? -1e30f : S[qs][sub][r] * SC;
                            p[sub][r] = __builtin_amdgcn_exp2f(sc);
                        }
                } else {
#pragma unroll
                    for (int sub = 0; sub < 4; ++sub)
#pragma unroll
                        for (int r = 0; r < 4; ++r)
                            p[sub][r] = __builtin_amdgcn_exp2f(S[qs][sub][r] * SC);
                }
                float ls = 0.f;
#pragma unroll
                for (int sub = 0; sub < 4; ++sub)
                    ls += (p[sub][0] + p[sub][1]) + (p[sub][2] + p[sub][3]);
                l_acc[qs] += ls;

                // pack P -> A-fragments: slot j of kg = (sub = kg*2 + (j>>2), r = j&3)
                u32x4 w0, w1;
                w0.x = cvt_pk_bf16(p[0][0], p[0][1]);
                w0.y = cvt_pk_bf16(p[0][2], p[0][3]);
                w0.z = cvt_pk_bf16(p[1][0], p[1][1]);
                w0.w = cvt_pk_bf16(p[1][2], p[1][3]);
                w1.x = cvt_pk_bf16(p[2][0], p[2][1]);
                w1.y = cvt_pk_bf16(p[2][2], p[2][3]);
                w1.z = cvt_pk_bf16(p[3][0], p[3][1]);
                w1.w = cvt_pk_bf16(p[3][2], p[3][3]);
                paf[qs][0] = __builtin_bit_cast(bf16x8, w0);
                paf[qs][1] = __builtin_bit_cast(bf16x8, w1);
            }

            // O += P V: V fragments shared across the 2 q-subtiles
#pragma unroll
            for (int nt = 0; nt < 8; ++nt) {
                bf16x8 vf0 = *(const bf16x8*)(&Vt[cur][kg0][nt * 16 + col][ko]);
                bf16x8 vf1 = *(const bf16x8*)(&Vt[cur][2 + kg0][nt * 16 + col][ko]);
#pragma unroll
                for (int qs = 0; qs < 2; ++qs) {
                    O[qs][nt] = __builtin_amdgcn_mfma_f32_16x16x32_bf16(paf[qs][0], vf0, O[qs][nt], 0, 0, 0);
                    O[qs][nt] = __builtin_amdgcn_mfma_f32_16x16x32_bf16(paf[qs][1], vf1, O[qs][nt], 0, 0, 0);
                }
            }
        }

        __syncthreads();   // next buffer staged (vmcnt drained) + all reads of cur done
        cur ^= 1;
    }

    // epilogue: l lives per lane at query=col; O rows are query=quad*4+r.
#pragma unroll
    for (int qs = 0; qs < 2; ++qs) {
        float s = l_acc[qs];
        s += __shfl_xor(s, 16);
        s += __shfl_xor(s, 32);
#pragma unroll
        for (int r = 0; r < 4; ++r) {
            const float inv = 1.0f / __shfl(s, quad * 4 + r);
            const int t = q0 + w * 32 + qs * 16 + quad * 4 + r;
            ushort* orow = attb + (size_t)(b * T + t) * C + h * D;
#pragma unroll
            for (int nt = 0; nt < 8; ++nt)
                orow[nt * 16 + col] = f2bf(O[qs][nt][r] * inv);
        }
    }
}

// -------------------- Launch --------------------
extern "C" void kernel_launch(void* const* d_in, const int* in_sizes, int n_in,
                              void* d_out, int out_size, void* d_ws, size_t ws_size,
                              hipStream_t stream) {
    const float* x  = (const float*)d_in[0];
    const float* Wk = (const float*)d_in[1];
    const float* Wv = (const float*)d_in[2];
    const float* Wq = (const float*)d_in[3];
    const float* Wp = (const float*)d_in[4];
    const float* bp = (const float*)d_in[5];
    float* out = (float*)d_out;

    char* ws = (char*)d_ws;
    ushort* xb    = (ushort*)ws;                                  // 16 MB (aliased by attb later)
    ushort* attb  = xb;
    ushort* qkv   = (ushort*)(ws + (size_t)16  * 1024 * 1024);    // 20 MB
    ushort* WcatT = (ushort*)(ws + (size_t)36  * 1024 * 1024);    // 2.5 MB
    ushort* WpT   = (ushort*)(ws + (size_t)39  * 1024 * 1024);    // 2 MB
    ushort* vbT   = (ushort*)(ws + (size_t)41  * 1024 * 1024);    // 2 MB

    // 1) conversions
    xcvt<<<(size_t)M_ROWS * C / (256 * 8), 256, 0, stream>>>(x, xb);
    wtrans_qkv<<<dim3(D / 64, C / 64, 2 + NQ), 256, 0, stream>>>(Wk, Wv, Wq, WcatT);
    wtrans_p<<<dim3(C / 64, C / 64), 256, 0, stream>>>(Wp, WpT);

    // 2) fused QKV GEMM: [8192,1024] @ [1024,1280] -> qkv bf16  (640 blocks)
    gemm_mfma<true><<<dim3(NTOT / 128, M_ROWS / 128), 256, 0, stream>>>(
        xb, WcatT, qkv, nullptr, NTOT);

    // 3) v transpose (with MFMA-fragment key permutation)
    vtrans<<<M_ROWS / 64, 256, 0, stream>>>(qkv, vbT);

    // 4) flash attention (R2 verified: 2-phase dbuf, 4 waves x 32q)
    attn_mfma<<<dim3(T / 128, NQ, B), 256, 0, stream>>>(qkv, vbT, attb);

    // 5) projection: [8192,1024] @ [1024,1024] + bp -> out f32  (512 blocks)
    gemm_mfma<false><<<dim3(C / 128, M_ROWS / 128), 256, 0, stream>>>(
        attb, WpT, out, bp, C);
}